// Round 3
// baseline (659.955 us; speedup 1.0000x reference)
//
#include <hip/hip_runtime.h>
#include <math.h>

#define G  17
#define Cg 32
#define B  4
#define C  544
#define H  96
#define W  96
#define HW (H*W)
#define TILES (HW/256)   // 36
#define BN_EPS 1e-5f

// ---------------------------------------------------------------------------
// Kernel 1: grouped 3x3 offset conv -> per-pixel affine aff[B][G][6][H][W]
// ---------------------------------------------------------------------------
__global__ __launch_bounds__(256) void offset_conv_kernel(
    const float* __restrict__ x, const float* __restrict__ w_off,
    const float* __restrict__ b_off, float* __restrict__ aff)
{
    __shared__ float wl[Cg*9*6];           // layout [i][t][c]
    const int blk  = blockIdx.x;           // b*G*TILES + g*TILES + tile
    const int tile = blk % TILES;
    const int g    = (blk / TILES) % G;
    const int b    = blk / (TILES*G);

    for (int l = threadIdx.x; l < Cg*9*6; l += 256) {
        int c = l % 6; int t = (l/6) % 9; int i = l/54;
        wl[l] = w_off[(size_t)(g*6 + c)*(Cg*9) + i*9 + t];
    }
    __syncthreads();

    const int p = tile*256 + threadIdx.x;
    const int h = p / W, w = p % W;

    float acc[6];
    #pragma unroll
    for (int c = 0; c < 6; ++c) acc[c] = b_off[g*6 + c];

    const float* xg = x + ((size_t)b*C + g*Cg)*HW;
    for (int i = 0; i < Cg; ++i) {
        const float* xc = xg + (size_t)i*HW;
        #pragma unroll
        for (int t = 0; t < 9; ++t) {
            const int dy = t/3 - 1, dx = t%3 - 1;
            const int yy = h + dy, xx = w + dx;
            float v = (yy >= 0 && yy < H && xx >= 0 && xx < W) ? xc[yy*W + xx] : 0.0f;
            #pragma unroll
            for (int c = 0; c < 6; ++c)
                acc[c] = fmaf(v, wl[(i*9 + t)*6 + c], acc[c]);
        }
    }

    float* ap = aff + ((size_t)(b*G + g)*6)*HW + p;
    #pragma unroll
    for (int c = 0; c < 6; ++c) ap[(size_t)c*HW] = acc[c];
}

// ---------------------------------------------------------------------------
// Kernel T: NCHW -> per-group channels-last  xT[(b*G+g)*HW + p][Cg]
// ---------------------------------------------------------------------------
__global__ __launch_bounds__(256) void transpose_kernel(
    const float* __restrict__ x, float* __restrict__ xT)
{
    __shared__ float t[256*33];            // +1 pad: conflict-free both phases
    const int blk  = blockIdx.x;
    const int tile = blk % TILES;
    const int g    = (blk / TILES) % G;
    const int b    = blk / (TILES*G);

    const float* xg = x + ((size_t)b*C + g*Cg)*HW + tile*256;
    #pragma unroll
    for (int i = 0; i < Cg; ++i)
        t[threadIdx.x*33 + i] = xg[(size_t)i*HW + threadIdx.x];
    __syncthreads();

    float4* dst = (float4*)(xT + ((size_t)(b*G + g)*HW + (size_t)tile*256)*Cg);
    #pragma unroll
    for (int r = 0; r < 8; ++r) {
        const int idx = r*256 + threadIdx.x;    // p = idx>>3, i4 = idx&7
        const int p = idx >> 3, i4 = idx & 7;
        const float* s = &t[p*33 + i4*4];
        dst[idx] = make_float4(s[0], s[1], s[2], s[3]);
    }
}

// ---------------------------------------------------------------------------
// Kernel 2 (channels-last): deformable conv + eval-BN + residual ReLU.
// lane = pixel; 4 bilinear corners per (k, 4-channel group) are contiguous
// 16B runs -> dwordx4; 32 f32 accumulators; weights in LDS [k][i][o] read at
// uniform addresses (broadcast).
// __launch_bounds__(256,4): force <=128 VGPR -> 4 waves/SIMD (was 140 VGPR,
// 2 waves/SIMD, latency-bound at VALUBusy=29%).
// ---------------------------------------------------------------------------
__global__ __launch_bounds__(256, 4) void deform_conv_cl_kernel(
    const float* __restrict__ x, const float* __restrict__ xT,
    const float* __restrict__ w_def, const float* __restrict__ aff,
    const float* __restrict__ gamma, const float* __restrict__ beta,
    const float* __restrict__ rmean, const float* __restrict__ rvar,
    float* __restrict__ out)
{
    __shared__ float wl[9*Cg*Cg];          // layout [k][i][o]
    const int blk  = blockIdx.x;
    const int tile = blk % TILES;
    const int g    = (blk / TILES) % G;
    const int b    = blk / (TILES*G);

    for (int l = threadIdx.x; l < 9*Cg*Cg; l += 256) {
        int o = l & 31; int i = (l >> 5) & 31; int k = l >> 10;
        wl[l] = w_def[(size_t)(g*Cg + o)*(Cg*9) + i*9 + k];
    }
    __syncthreads();

    const int p = tile*256 + threadIdx.x;
    const int h = p / W, w = p % W;

    const float* ap = aff + ((size_t)(b*G + g)*6)*HW + p;
    const float a0 = ap[0*(size_t)HW], a1 = ap[1*(size_t)HW], a2 = ap[2*(size_t)HW];
    const float a3 = ap[3*(size_t)HW], a4 = ap[4*(size_t)HW], a5 = ap[5*(size_t)HW];

    float acc[Cg];
    #pragma unroll
    for (int o = 0; o < Cg; ++o) acc[o] = 0.0f;

    const float* xgT = xT + (size_t)(b*G + g)*HW*Cg;

    #pragma unroll
    for (int k = 0; k < 9; ++k) {
        const float kyf = (float)(k/3 - 1);
        const float kxf = (float)(k%3 - 1);
        const float offy = a0*kyf + a1*kxf + a2;
        const float offx = a3*kyf + a4*kxf + a5;
        const float py = (float)h + kyf + offy;
        const float px = (float)w + kxf + offx;
        const float y0f = floorf(py), x0f = floorf(px);
        const float fy = py - y0f,   fx = px - x0f;
        const int y0 = (int)y0f, x0 = (int)x0f;
        const int y1 = y0 + 1,   x1 = x0 + 1;
        const bool vy0 = (y0 >= 0) && (y0 < H);
        const bool vy1 = (y1 >= 0) && (y1 < H);
        const bool vx0 = (x0 >= 0) && (x0 < W);
        const bool vx1 = (x1 >= 0) && (x1 < W);
        const float w00 = (vy0 && vx0) ? (1.0f - fy)*(1.0f - fx) : 0.0f;
        const float w01 = (vy0 && vx1) ? (1.0f - fy)*fx          : 0.0f;
        const float w10 = (vy1 && vx0) ? fy*(1.0f - fx)          : 0.0f;
        const float w11 = (vy1 && vx1) ? fy*fx                   : 0.0f;
        const int y0c = min(max(y0, 0), H-1), y1c = min(max(y1, 0), H-1);
        const int x0c = min(max(x0, 0), W-1), x1c = min(max(x1, 0), W-1);
        const float4* c00 = (const float4*)(xgT + (size_t)(y0c*W + x0c)*Cg);
        const float4* c01 = (const float4*)(xgT + (size_t)(y0c*W + x1c)*Cg);
        const float4* c10 = (const float4*)(xgT + (size_t)(y1c*W + x0c)*Cg);
        const float4* c11 = (const float4*)(xgT + (size_t)(y1c*W + x1c)*Cg);

        const float* wk = &wl[k*Cg*Cg];
        #pragma unroll
        for (int i4 = 0; i4 < 8; ++i4) {
            const float4 v00 = c00[i4], v01 = c01[i4];
            const float4 v10 = c10[i4], v11 = c11[i4];
            float4 v;
            v.x = w00*v00.x + w01*v01.x + w10*v10.x + w11*v11.x;
            v.y = w00*v00.y + w01*v01.y + w10*v10.y + w11*v11.y;
            v.z = w00*v00.z + w01*v01.z + w10*v10.z + w11*v11.z;
            v.w = w00*v00.w + w01*v01.w + w10*v10.w + w11*v11.w;
            const float* w0 = &wk[(i4*4 + 0)*Cg];
            const float* w1 = &wk[(i4*4 + 1)*Cg];
            const float* w2 = &wk[(i4*4 + 2)*Cg];
            const float* w3 = &wk[(i4*4 + 3)*Cg];
            #pragma unroll
            for (int o = 0; o < Cg; ++o) {
                float a = acc[o];
                a = fmaf(v.x, w0[o], a);
                a = fmaf(v.y, w1[o], a);
                a = fmaf(v.z, w2[o], a);
                a = fmaf(v.w, w3[o], a);
                acc[o] = a;
            }
        }
    }

    const float* xg = x + ((size_t)b*C + g*Cg)*HW;
    float* op = out + ((size_t)b*C + g*Cg)*HW + p;
    #pragma unroll
    for (int o = 0; o < Cg; ++o) {
        const int c = g*Cg + o;
        const float inv = rsqrtf(rvar[c] + BN_EPS);
        float val = (acc[o] - rmean[c]) * (inv * gamma[c]) + beta[c];
        val += xg[(size_t)o*HW + p];
        op[(size_t)o*HW] = fmaxf(val, 0.0f);
    }
}

// ---------------------------------------------------------------------------
// Fallback (NCHW path) if ws is too small for the transposed copy.
// ---------------------------------------------------------------------------
__global__ __launch_bounds__(256) void deform_conv_kernel(
    const float* __restrict__ x, const float* __restrict__ w_def,
    const float* __restrict__ aff, const float* __restrict__ gamma,
    const float* __restrict__ beta, const float* __restrict__ rmean,
    const float* __restrict__ rvar, float* __restrict__ out)
{
    __shared__ float wl[9*Cg*Cg];
    const int blk  = blockIdx.x;
    const int tile = blk % TILES;
    const int g    = (blk / TILES) % G;
    const int b    = blk / (TILES*G);

    for (int l = threadIdx.x; l < 9*Cg*Cg; l += 256) {
        int o = l & 31; int i = (l >> 5) & 31; int k = l >> 10;
        wl[l] = w_def[(size_t)(g*Cg + o)*(Cg*9) + i*9 + k];
    }
    __syncthreads();

    const int p = tile*256 + threadIdx.x;
    const int h = p / W, w = p % W;

    const float* ap = aff + ((size_t)(b*G + g)*6)*HW + p;
    const float a0 = ap[0*(size_t)HW], a1 = ap[1*(size_t)HW], a2 = ap[2*(size_t)HW];
    const float a3 = ap[3*(size_t)HW], a4 = ap[4*(size_t)HW], a5 = ap[5*(size_t)HW];

    float acc[Cg];
    #pragma unroll
    for (int o = 0; o < Cg; ++o) acc[o] = 0.0f;

    const float* xg = x + ((size_t)b*C + g*Cg)*HW;

    #pragma unroll
    for (int k = 0; k < 9; ++k) {
        const float kyf = (float)(k/3 - 1);
        const float kxf = (float)(k%3 - 1);
        const float offy = a0*kyf + a1*kxf + a2;
        const float offx = a3*kyf + a4*kxf + a5;
        const float py = (float)h + kyf + offy;
        const float px = (float)w + kxf + offx;
        const float y0f = floorf(py), x0f = floorf(px);
        const float fy = py - y0f,   fx = px - x0f;
        const int y0 = (int)y0f, x0 = (int)x0f;
        const int y1 = y0 + 1,   x1 = x0 + 1;
        const bool vy0 = (y0 >= 0) && (y0 < H);
        const bool vy1 = (y1 >= 0) && (y1 < H);
        const bool vx0 = (x0 >= 0) && (x0 < W);
        const bool vx1 = (x1 >= 0) && (x1 < W);
        const float w00 = (vy0 && vx0) ? (1.0f - fy)*(1.0f - fx) : 0.0f;
        const float w01 = (vy0 && vx1) ? (1.0f - fy)*fx          : 0.0f;
        const float w10 = (vy1 && vx0) ? fy*(1.0f - fx)          : 0.0f;
        const float w11 = (vy1 && vx1) ? fy*fx                   : 0.0f;
        const int y0c = min(max(y0, 0), H-1), y1c = min(max(y1, 0), H-1);
        const int x0c = min(max(x0, 0), W-1), x1c = min(max(x1, 0), W-1);
        const int p00 = y0c*W + x0c, p01 = y0c*W + x1c;
        const int p10 = y1c*W + x0c, p11 = y1c*W + x1c;

        const float* wk = &wl[k*Cg*Cg];
        for (int i = 0; i < Cg; ++i) {
            const float* xc = xg + (size_t)i*HW;
            const float v = w00*xc[p00] + w01*xc[p01] + w10*xc[p10] + w11*xc[p11];
            #pragma unroll
            for (int o = 0; o < Cg; ++o)
                acc[o] = fmaf(v, wk[i*Cg + o], acc[o]);
        }
    }

    float* op = out + ((size_t)b*C + g*Cg)*HW + p;
    #pragma unroll
    for (int o = 0; o < Cg; ++o) {
        const int c = g*Cg + o;
        const float inv = rsqrtf(rvar[c] + BN_EPS);
        float val = (acc[o] - rmean[c]) * (inv * gamma[c]) + beta[c];
        val += xg[(size_t)o*HW + p];
        op[(size_t)o*HW] = fmaxf(val, 0.0f);
    }
}

// ---------------------------------------------------------------------------
extern "C" void kernel_launch(void* const* d_in, const int* in_sizes, int n_in,
                              void* d_out, int out_size, void* d_ws, size_t ws_size,
                              hipStream_t stream) {
    const float* x     = (const float*)d_in[0];
    const float* w_off = (const float*)d_in[1];
    const float* b_off = (const float*)d_in[2];
    const float* w_def = (const float*)d_in[3];
    const float* gamma = (const float*)d_in[4];
    const float* beta  = (const float*)d_in[5];
    const float* rmean = (const float*)d_in[6];
    const float* rvar  = (const float*)d_in[7];
    float* out = (float*)d_out;

    const size_t AFF_BYTES = (size_t)B*G*6*HW*sizeof(float);   // ~15.0 MB
    const size_t XT_BYTES  = (size_t)B*G*HW*Cg*sizeof(float);  // ~80.2 MB
    float* aff = (float*)d_ws;

    const int nblk = B * G * TILES;   // 4*17*36 = 2448
    offset_conv_kernel<<<nblk, 256, 0, stream>>>(x, w_off, b_off, aff);

    if (ws_size >= AFF_BYTES + XT_BYTES) {
        float* xT = (float*)((char*)d_ws + AFF_BYTES);
        transpose_kernel<<<nblk, 256, 0, stream>>>(x, xT);
        deform_conv_cl_kernel<<<nblk, 256, 0, stream>>>(x, xT, w_def, aff, gamma,
                                                        beta, rmean, rvar, out);
    } else {
        deform_conv_kernel<<<nblk, 256, 0, stream>>>(x, w_def, aff, gamma, beta,
                                                     rmean, rvar, out);
    }
}

// Round 4
// 468.346 us; speedup vs baseline: 1.4091x; 1.4091x over previous
//
#include <hip/hip_runtime.h>
#include <math.h>

#define G  17
#define Cg 32
#define B  4
#define C  544
#define H  96
#define W  96
#define HW (H*W)
#define TILES (HW/256)   // 36
#define NBLK (B*G*TILES) // 2448 (divisible by 8)
#define BN_EPS 1e-5f

// XCD-chunked swizzle: consecutive hardware blockIdx round-robin across the
// 8 XCDs; remap so each XCD gets a CONTIGUOUS logical range (same (b,g)
// slice stays in one XCD's L2). 2448 % 8 == 0 -> bijective.
__device__ __forceinline__ int swizzle_blk(int blk) {
    return (blk & 7) * (NBLK / 8) + (blk >> 3);
}

// ---------------------------------------------------------------------------
// Kernel 1: grouped 3x3 offset conv -> per-pixel affine aff[B][G][6][H][W]
// ---------------------------------------------------------------------------
__global__ __launch_bounds__(256) void offset_conv_kernel(
    const float* __restrict__ x, const float* __restrict__ w_off,
    const float* __restrict__ b_off, float* __restrict__ aff)
{
    __shared__ float wl[Cg*9*6];           // layout [i][t][c]
    const int blk  = swizzle_blk(blockIdx.x);
    const int tile = blk % TILES;
    const int g    = (blk / TILES) % G;
    const int b    = blk / (TILES*G);

    for (int l = threadIdx.x; l < Cg*9*6; l += 256) {
        int c = l % 6; int t = (l/6) % 9; int i = l/54;
        wl[l] = w_off[(size_t)(g*6 + c)*(Cg*9) + i*9 + t];
    }
    __syncthreads();

    const int p = tile*256 + threadIdx.x;
    const int h = p / W, w = p % W;

    float acc[6];
    #pragma unroll
    for (int c = 0; c < 6; ++c) acc[c] = b_off[g*6 + c];

    const float* xg = x + ((size_t)b*C + g*Cg)*HW;
    for (int i = 0; i < Cg; ++i) {
        const float* xc = xg + (size_t)i*HW;
        #pragma unroll
        for (int t = 0; t < 9; ++t) {
            const int dy = t/3 - 1, dx = t%3 - 1;
            const int yy = h + dy, xx = w + dx;
            float v = (yy >= 0 && yy < H && xx >= 0 && xx < W) ? xc[yy*W + xx] : 0.0f;
            #pragma unroll
            for (int c = 0; c < 6; ++c)
                acc[c] = fmaf(v, wl[(i*9 + t)*6 + c], acc[c]);
        }
    }

    float* ap = aff + ((size_t)(b*G + g)*6)*HW + p;
    #pragma unroll
    for (int c = 0; c < 6; ++c) ap[(size_t)c*HW] = acc[c];
}

// ---------------------------------------------------------------------------
// Kernel T: NCHW -> per-group channels-last  xT[(b*G+g)*HW + p][Cg]
// Same swizzle as the deform kernel -> producer/consumer share an XCD L2.
// ---------------------------------------------------------------------------
__global__ __launch_bounds__(256) void transpose_kernel(
    const float* __restrict__ x, float* __restrict__ xT)
{
    __shared__ float t[256*33];            // +1 pad: conflict-free both phases
    const int blk  = swizzle_blk(blockIdx.x);
    const int tile = blk % TILES;
    const int g    = (blk / TILES) % G;
    const int b    = blk / (TILES*G);

    const float* xg = x + ((size_t)b*C + g*Cg)*HW + tile*256;
    #pragma unroll
    for (int i = 0; i < Cg; ++i)
        t[threadIdx.x*33 + i] = xg[(size_t)i*HW + threadIdx.x];
    __syncthreads();

    float4* dst = (float4*)(xT + ((size_t)(b*G + g)*HW + (size_t)tile*256)*Cg);
    #pragma unroll
    for (int r = 0; r < 8; ++r) {
        const int idx = r*256 + threadIdx.x;    // p = idx>>3, i4 = idx&7
        const int p = idx >> 3, i4 = idx & 7;
        const float* s = &t[p*33 + i4*4];
        dst[idx] = make_float4(s[0], s[1], s[2], s[3]);
    }
}

// ---------------------------------------------------------------------------
// Kernel 2 (channels-last): deformable conv + eval-BN + residual ReLU.
// lane = pixel; 4 bilinear corners per (k, 4-channel group) are contiguous
// 16B runs -> dwordx4; 32 f32 accumulators; weights in LDS [k][i][o] read at
// uniform addresses (broadcast). NO min-waves clamp: (256,4) forced 64 VGPR
// and spilled (FETCH 152->925 MB, dur +35%). Natural 140 VGPR is the min
// pressure of this structure.
// ---------------------------------------------------------------------------
__global__ __launch_bounds__(256) void deform_conv_cl_kernel(
    const float* __restrict__ x, const float* __restrict__ xT,
    const float* __restrict__ w_def, const float* __restrict__ aff,
    const float* __restrict__ gamma, const float* __restrict__ beta,
    const float* __restrict__ rmean, const float* __restrict__ rvar,
    float* __restrict__ out)
{
    __shared__ float wl[9*Cg*Cg];          // layout [k][i][o]
    const int blk  = swizzle_blk(blockIdx.x);
    const int tile = blk % TILES;
    const int g    = (blk / TILES) % G;
    const int b    = blk / (TILES*G);

    for (int l = threadIdx.x; l < 9*Cg*Cg; l += 256) {
        int o = l & 31; int i = (l >> 5) & 31; int k = l >> 10;
        wl[l] = w_def[(size_t)(g*Cg + o)*(Cg*9) + i*9 + k];
    }
    __syncthreads();

    const int p = tile*256 + threadIdx.x;
    const int h = p / W, w = p % W;

    const float* ap = aff + ((size_t)(b*G + g)*6)*HW + p;
    const float a0 = ap[0*(size_t)HW], a1 = ap[1*(size_t)HW], a2 = ap[2*(size_t)HW];
    const float a3 = ap[3*(size_t)HW], a4 = ap[4*(size_t)HW], a5 = ap[5*(size_t)HW];

    float acc[Cg];
    #pragma unroll
    for (int o = 0; o < Cg; ++o) acc[o] = 0.0f;

    const float* xgT = xT + (size_t)(b*G + g)*HW*Cg;

    #pragma unroll
    for (int k = 0; k < 9; ++k) {
        const float kyf = (float)(k/3 - 1);
        const float kxf = (float)(k%3 - 1);
        const float offy = a0*kyf + a1*kxf + a2;
        const float offx = a3*kyf + a4*kxf + a5;
        const float py = (float)h + kyf + offy;
        const float px = (float)w + kxf + offx;
        const float y0f = floorf(py), x0f = floorf(px);
        const float fy = py - y0f,   fx = px - x0f;
        const int y0 = (int)y0f, x0 = (int)x0f;
        const int y1 = y0 + 1,   x1 = x0 + 1;
        const bool vy0 = (y0 >= 0) && (y0 < H);
        const bool vy1 = (y1 >= 0) && (y1 < H);
        const bool vx0 = (x0 >= 0) && (x0 < W);
        const bool vx1 = (x1 >= 0) && (x1 < W);
        const float w00 = (vy0 && vx0) ? (1.0f - fy)*(1.0f - fx) : 0.0f;
        const float w01 = (vy0 && vx1) ? (1.0f - fy)*fx          : 0.0f;
        const float w10 = (vy1 && vx0) ? fy*(1.0f - fx)          : 0.0f;
        const float w11 = (vy1 && vx1) ? fy*fx                   : 0.0f;
        const int y0c = min(max(y0, 0), H-1), y1c = min(max(y1, 0), H-1);
        const int x0c = min(max(x0, 0), W-1), x1c = min(max(x1, 0), W-1);
        const float4* c00 = (const float4*)(xgT + (size_t)(y0c*W + x0c)*Cg);
        const float4* c01 = (const float4*)(xgT + (size_t)(y0c*W + x1c)*Cg);
        const float4* c10 = (const float4*)(xgT + (size_t)(y1c*W + x0c)*Cg);
        const float4* c11 = (const float4*)(xgT + (size_t)(y1c*W + x1c)*Cg);

        const float* wk = &wl[k*Cg*Cg];
        #pragma unroll 2
        for (int i4 = 0; i4 < 8; ++i4) {
            const float4 v00 = c00[i4], v01 = c01[i4];
            const float4 v10 = c10[i4], v11 = c11[i4];
            float4 v;
            v.x = w00*v00.x + w01*v01.x + w10*v10.x + w11*v11.x;
            v.y = w00*v00.y + w01*v01.y + w10*v10.y + w11*v11.y;
            v.z = w00*v00.z + w01*v01.z + w10*v10.z + w11*v11.z;
            v.w = w00*v00.w + w01*v01.w + w10*v10.w + w11*v11.w;
            const float* w0 = &wk[(i4*4 + 0)*Cg];
            const float* w1 = &wk[(i4*4 + 1)*Cg];
            const float* w2 = &wk[(i4*4 + 2)*Cg];
            const float* w3 = &wk[(i4*4 + 3)*Cg];
            #pragma unroll
            for (int o = 0; o < Cg; ++o) {
                float a = acc[o];
                a = fmaf(v.x, w0[o], a);
                a = fmaf(v.y, w1[o], a);
                a = fmaf(v.z, w2[o], a);
                a = fmaf(v.w, w3[o], a);
                acc[o] = a;
            }
        }
    }

    const float* xg = x + ((size_t)b*C + g*Cg)*HW;
    float* op = out + ((size_t)b*C + g*Cg)*HW + p;
    #pragma unroll
    for (int o = 0; o < Cg; ++o) {
        const int c = g*Cg + o;
        const float inv = rsqrtf(rvar[c] + BN_EPS);
        float val = (acc[o] - rmean[c]) * (inv * gamma[c]) + beta[c];
        val += xg[(size_t)o*HW + p];
        op[(size_t)o*HW] = fmaxf(val, 0.0f);
    }
}

// ---------------------------------------------------------------------------
// Fallback (NCHW path) if ws is too small for the transposed copy.
// ---------------------------------------------------------------------------
__global__ __launch_bounds__(256) void deform_conv_kernel(
    const float* __restrict__ x, const float* __restrict__ w_def,
    const float* __restrict__ aff, const float* __restrict__ gamma,
    const float* __restrict__ beta, const float* __restrict__ rmean,
    const float* __restrict__ rvar, float* __restrict__ out)
{
    __shared__ float wl[9*Cg*Cg];
    const int blk  = swizzle_blk(blockIdx.x);
    const int tile = blk % TILES;
    const int g    = (blk / TILES) % G;
    const int b    = blk / (TILES*G);

    for (int l = threadIdx.x; l < 9*Cg*Cg; l += 256) {
        int o = l & 31; int i = (l >> 5) & 31; int k = l >> 10;
        wl[l] = w_def[(size_t)(g*Cg + o)*(Cg*9) + i*9 + k];
    }
    __syncthreads();

    const int p = tile*256 + threadIdx.x;
    const int h = p / W, w = p % W;

    const float* ap = aff + ((size_t)(b*G + g)*6)*HW + p;
    const float a0 = ap[0*(size_t)HW], a1 = ap[1*(size_t)HW], a2 = ap[2*(size_t)HW];
    const float a3 = ap[3*(size_t)HW], a4 = ap[4*(size_t)HW], a5 = ap[5*(size_t)HW];

    float acc[Cg];
    #pragma unroll
    for (int o = 0; o < Cg; ++o) acc[o] = 0.0f;

    const float* xg = x + ((size_t)b*C + g*Cg)*HW;

    #pragma unroll
    for (int k = 0; k < 9; ++k) {
        const float kyf = (float)(k/3 - 1);
        const float kxf = (float)(k%3 - 1);
        const float offy = a0*kyf + a1*kxf + a2;
        const float offx = a3*kyf + a4*kxf + a5;
        const float py = (float)h + kyf + offy;
        const float px = (float)w + kxf + offx;
        const float y0f = floorf(py), x0f = floorf(px);
        const float fy = py - y0f,   fx = px - x0f;
        const int y0 = (int)y0f, x0 = (int)x0f;
        const int y1 = y0 + 1,   x1 = x0 + 1;
        const bool vy0 = (y0 >= 0) && (y0 < H);
        const bool vy1 = (y1 >= 0) && (y1 < H);
        const bool vx0 = (x0 >= 0) && (x0 < W);
        const bool vx1 = (x1 >= 0) && (x1 < W);
        const float w00 = (vy0 && vx0) ? (1.0f - fy)*(1.0f - fx) : 0.0f;
        const float w01 = (vy0 && vx1) ? (1.0f - fy)*fx          : 0.0f;
        const float w10 = (vy1 && vx0) ? fy*(1.0f - fx)          : 0.0f;
        const float w11 = (vy1 && vx1) ? fy*fx                   : 0.0f;
        const int y0c = min(max(y0, 0), H-1), y1c = min(max(y1, 0), H-1);
        const int x0c = min(max(x0, 0), W-1), x1c = min(max(x1, 0), W-1);
        const int p00 = y0c*W + x0c, p01 = y0c*W + x1c;
        const int p10 = y1c*W + x0c, p11 = y1c*W + x1c;

        const float* wk = &wl[k*Cg*Cg];
        for (int i = 0; i < Cg; ++i) {
            const float* xc = xg + (size_t)i*HW;
            const float v = w00*xc[p00] + w01*xc[p01] + w10*xc[p10] + w11*xc[p11];
            #pragma unroll
            for (int o = 0; o < Cg; ++o)
                acc[o] = fmaf(v, wk[i*Cg + o], acc[o]);
        }
    }

    float* op = out + ((size_t)b*C + g*Cg)*HW + p;
    #pragma unroll
    for (int o = 0; o < Cg; ++o) {
        const int c = g*Cg + o;
        const float inv = rsqrtf(rvar[c] + BN_EPS);
        float val = (acc[o] - rmean[c]) * (inv * gamma[c]) + beta[c];
        val += xg[(size_t)o*HW + p];
        op[(size_t)o*HW] = fmaxf(val, 0.0f);
    }
}

// ---------------------------------------------------------------------------
extern "C" void kernel_launch(void* const* d_in, const int* in_sizes, int n_in,
                              void* d_out, int out_size, void* d_ws, size_t ws_size,
                              hipStream_t stream) {
    const float* x     = (const float*)d_in[0];
    const float* w_off = (const float*)d_in[1];
    const float* b_off = (const float*)d_in[2];
    const float* w_def = (const float*)d_in[3];
    const float* gamma = (const float*)d_in[4];
    const float* beta  = (const float*)d_in[5];
    const float* rmean = (const float*)d_in[6];
    const float* rvar  = (const float*)d_in[7];
    float* out = (float*)d_out;

    const size_t AFF_BYTES = (size_t)B*G*6*HW*sizeof(float);   // ~15.0 MB
    const size_t XT_BYTES  = (size_t)B*G*HW*Cg*sizeof(float);  // ~80.2 MB
    float* aff = (float*)d_ws;

    offset_conv_kernel<<<NBLK, 256, 0, stream>>>(x, w_off, b_off, aff);

    if (ws_size >= AFF_BYTES + XT_BYTES) {
        float* xT = (float*)((char*)d_ws + AFF_BYTES);
        transpose_kernel<<<NBLK, 256, 0, stream>>>(x, xT);
        deform_conv_cl_kernel<<<NBLK, 256, 0, stream>>>(x, xT, w_def, aff, gamma,
                                                        beta, rmean, rvar, out);
    } else {
        deform_conv_kernel<<<NBLK, 256, 0, stream>>>(x, w_def, aff, gamma, beta,
                                                     rmean, rvar, out);
    }
}

// Round 5
// 411.627 us; speedup vs baseline: 1.6033x; 1.1378x over previous
//
#include <hip/hip_runtime.h>
#include <math.h>

#define G  17
#define Cg 32
#define B  4
#define C  544
#define H  96
#define W  96
#define HW (H*W)
#define TILES (HW/256)   // 36
#define NBLK (B*G*TILES) // 2448 (divisible by 8)
#define BN_EPS 1e-5f

typedef float  f32x4  __attribute__((ext_vector_type(4)));
typedef short  short8 __attribute__((ext_vector_type(8)));

// LDS layout (bytes). A: 256 px rows of 32 bf16 (64B) padded to 80B ->
// bank-start (px*20)%32 cycles over 8 distinct banks => <=2-way (free).
// B: 32 o rows of 288 bf16 (576B) padded to 592B -> same property.
#define A_STRIDE 80
#define B_STRIDE 592
#define A_BYTES  (256*A_STRIDE)   // 20480
#define B_BYTES  (Cg*B_STRIDE)    // 18944

// XCD-chunked swizzle (round-4 verified: FETCH 925->87 MB).
__device__ __forceinline__ int swizzle_blk(int blk) {
    return (blk & 7) * (NBLK / 8) + (blk >> 3);
}

// ---------------------------------------------------------------------------
// Kernel 1: grouped 3x3 offset conv -> per-pixel affine aff[B][G][6][H][W]
// ---------------------------------------------------------------------------
__global__ __launch_bounds__(256) void offset_conv_kernel(
    const float* __restrict__ x, const float* __restrict__ w_off,
    const float* __restrict__ b_off, float* __restrict__ aff)
{
    __shared__ float wl[Cg*9*6];           // layout [i][t][c]
    const int blk  = swizzle_blk(blockIdx.x);
    const int tile = blk % TILES;
    const int g    = (blk / TILES) % G;
    const int b    = blk / (TILES*G);

    for (int l = threadIdx.x; l < Cg*9*6; l += 256) {
        int c = l % 6; int t = (l/6) % 9; int i = l/54;
        wl[l] = w_off[(size_t)(g*6 + c)*(Cg*9) + i*9 + t];
    }
    __syncthreads();

    const int p = tile*256 + threadIdx.x;
    const int h = p / W, w = p % W;

    float acc[6];
    #pragma unroll
    for (int c = 0; c < 6; ++c) acc[c] = b_off[g*6 + c];

    const float* xg = x + ((size_t)b*C + g*Cg)*HW;
    for (int i = 0; i < Cg; ++i) {
        const float* xc = xg + (size_t)i*HW;
        #pragma unroll
        for (int t = 0; t < 9; ++t) {
            const int dy = t/3 - 1, dx = t%3 - 1;
            const int yy = h + dy, xx = w + dx;
            float v = (yy >= 0 && yy < H && xx >= 0 && xx < W) ? xc[yy*W + xx] : 0.0f;
            #pragma unroll
            for (int c = 0; c < 6; ++c)
                acc[c] = fmaf(v, wl[(i*9 + t)*6 + c], acc[c]);
        }
    }

    float* ap = aff + ((size_t)(b*G + g)*6)*HW + p;
    #pragma unroll
    for (int c = 0; c < 6; ++c) ap[(size_t)c*HW] = acc[c];
}

// ---------------------------------------------------------------------------
// Kernel T: NCHW -> per-group channels-last  xT[(b*G+g)*HW + p][Cg]  (fp32)
// ---------------------------------------------------------------------------
__global__ __launch_bounds__(256) void transpose_kernel(
    const float* __restrict__ x, float* __restrict__ xT)
{
    __shared__ float t[256*33];            // +1 pad: conflict-free both phases
    const int blk  = swizzle_blk(blockIdx.x);
    const int tile = blk % TILES;
    const int g    = (blk / TILES) % G;
    const int b    = blk / (TILES*G);

    const float* xg = x + ((size_t)b*C + g*Cg)*HW + tile*256;
    #pragma unroll
    for (int i = 0; i < Cg; ++i)
        t[threadIdx.x*33 + i] = xg[(size_t)i*HW + threadIdx.x];
    __syncthreads();

    float4* dst = (float4*)(xT + ((size_t)(b*G + g)*HW + (size_t)tile*256)*Cg);
    #pragma unroll
    for (int r = 0; r < 8; ++r) {
        const int idx = r*256 + threadIdx.x;
        const int p = idx >> 3, i4 = idx & 7;
        const float* s = &t[p*33 + i4*4];
        dst[idx] = make_float4(s[0], s[1], s[2], s[3]);
    }
}

// ---------------------------------------------------------------------------
// Kernel 2: im2col-in-LDS + bf16 MFMA deformable conv + BN + residual ReLU.
// Per tap t: every thread bilinearly samples its pixel's 32 channels (f32
// gather from xT, f32 blend), converts to bf16, writes one 64B row to LDS;
// then each of the 4 waves does 4 Mtile x 2 Ntile mfma_16x16x32_bf16 (K=32
// = the 32 channels of tap t). Weights staged once in LDS (bf16).
// Fragment maps (m89-verified): A row=lane&15, k=(lane>>4)*8+e;
//                               D col=lane&15, row=(lane>>4)*4+reg.
// ---------------------------------------------------------------------------
typedef struct __align__(8) { __bf16 v[4]; } bf16x4_t;

__global__ __launch_bounds__(256) void deform_mfma_kernel(
    const float* __restrict__ x, const float* __restrict__ xT,
    const float* __restrict__ w_def, const float* __restrict__ aff,
    const float* __restrict__ gamma, const float* __restrict__ beta,
    const float* __restrict__ rmean, const float* __restrict__ rvar,
    float* __restrict__ out)
{
    __shared__ char smem[A_BYTES + B_BYTES];
    char* Asm = smem;
    char* Bsm = smem + A_BYTES;

    const int blk  = swizzle_blk(blockIdx.x);
    const int tile = blk % TILES;
    const int g    = (blk / TILES) % G;
    const int b    = blk / (TILES*G);
    const int tid  = threadIdx.x;
    const int lane = tid & 63;
    const int wv   = tid >> 6;

    // ---- stage group weights to LDS (bf16): Bsm[o][K=t*32+i] ----
    for (int l = tid; l < Cg*288; l += 256) {
        const int o = l / 288, K = l % 288;
        const int t = K >> 5, i = K & 31;
        const float wt = w_def[(size_t)(g*Cg + o)*(Cg*9) + i*9 + t];
        *(__bf16*)(Bsm + o*B_STRIDE + K*2) = (__bf16)wt;
    }

    const int p = tile*256 + tid;
    const int h = p / W, w = p % W;

    const float* ap = aff + ((size_t)(b*G + g)*6)*HW + p;
    const float a0 = ap[0*(size_t)HW], a1 = ap[1*(size_t)HW], a2 = ap[2*(size_t)HW];
    const float a3 = ap[3*(size_t)HW], a4 = ap[4*(size_t)HW], a5 = ap[5*(size_t)HW];

    const float* xgT = xT + (size_t)(b*G + g)*HW*Cg;

    f32x4 acc[4][2];
    #pragma unroll
    for (int m = 0; m < 4; ++m)
        #pragma unroll
        for (int n = 0; n < 2; ++n)
            acc[m][n] = (f32x4){0.f, 0.f, 0.f, 0.f};

    char* arow = Asm + tid*A_STRIDE;
    const int r15  = lane & 15;
    const int koff = lane >> 4;

    #pragma unroll 1
    for (int t = 0; t < 9; ++t) {
        // ---- sampling phase: this thread's pixel, tap t ----
        const float kyf = (float)(t/3 - 1);
        const float kxf = (float)(t%3 - 1);
        const float offy = a0*kyf + a1*kxf + a2;
        const float offx = a3*kyf + a4*kxf + a5;
        const float py = (float)h + kyf + offy;
        const float px = (float)w + kxf + offx;
        const float y0f = floorf(py), x0f = floorf(px);
        const float fy = py - y0f,   fx = px - x0f;
        const int y0 = (int)y0f, x0 = (int)x0f;
        const int y1 = y0 + 1,   x1 = x0 + 1;
        const bool vy0 = (y0 >= 0) && (y0 < H);
        const bool vy1 = (y1 >= 0) && (y1 < H);
        const bool vx0 = (x0 >= 0) && (x0 < W);
        const bool vx1 = (x1 >= 0) && (x1 < W);
        const float w00 = (vy0 && vx0) ? (1.0f - fy)*(1.0f - fx) : 0.0f;
        const float w01 = (vy0 && vx1) ? (1.0f - fy)*fx          : 0.0f;
        const float w10 = (vy1 && vx0) ? fy*(1.0f - fx)          : 0.0f;
        const float w11 = (vy1 && vx1) ? fy*fx                   : 0.0f;
        const int y0c = min(max(y0, 0), H-1), y1c = min(max(y1, 0), H-1);
        const int x0c = min(max(x0, 0), W-1), x1c = min(max(x1, 0), W-1);
        const float4* c00 = (const float4*)(xgT + (size_t)(y0c*W + x0c)*Cg);
        const float4* c01 = (const float4*)(xgT + (size_t)(y0c*W + x1c)*Cg);
        const float4* c10 = (const float4*)(xgT + (size_t)(y1c*W + x0c)*Cg);
        const float4* c11 = (const float4*)(xgT + (size_t)(y1c*W + x1c)*Cg);

        #pragma unroll
        for (int i4 = 0; i4 < 8; ++i4) {
            const float4 v00 = c00[i4], v01 = c01[i4];
            const float4 v10 = c10[i4], v11 = c11[i4];
            bf16x4_t q;
            q.v[0] = (__bf16)(w00*v00.x + w01*v01.x + w10*v10.x + w11*v11.x);
            q.v[1] = (__bf16)(w00*v00.y + w01*v01.y + w10*v10.y + w11*v11.y);
            q.v[2] = (__bf16)(w00*v00.z + w01*v01.z + w10*v10.z + w11*v11.z);
            q.v[3] = (__bf16)(w00*v00.w + w01*v01.w + w10*v10.w + w11*v11.w);
            *(bf16x4_t*)(arow + i4*8) = q;
        }
        __syncthreads();

        // ---- MFMA phase: K=32 (channels of tap t) ----
        short8 af[4];
        #pragma unroll
        for (int m = 0; m < 4; ++m)
            af[m] = *(const short8*)(Asm + (wv*64 + m*16 + r15)*A_STRIDE + koff*16);
        #pragma unroll
        for (int n = 0; n < 2; ++n) {
            const short8 bf = *(const short8*)(Bsm + (n*16 + r15)*B_STRIDE + t*64 + koff*16);
            #pragma unroll
            for (int m = 0; m < 4; ++m)
                acc[m][n] = __builtin_amdgcn_mfma_f32_16x16x32_bf16(af[m], bf, acc[m][n], 0, 0, 0);
        }
        __syncthreads();
    }

    // ---- epilogue: BN + residual + ReLU, 16B-chunk stores ----
    #pragma unroll
    for (int m = 0; m < 4; ++m) {
        const int pxg = tile*256 + wv*64 + m*16 + (lane >> 4)*4;
        #pragma unroll
        for (int n = 0; n < 2; ++n) {
            const int o = n*16 + r15;
            const int c = g*Cg + o;
            const float inv   = rsqrtf(rvar[c] + BN_EPS);
            const float scale = inv * gamma[c];
            const float shift = beta[c] - rmean[c]*scale;
            const size_t base = ((size_t)b*C + c)*HW + pxg;
            const float4 res = *(const float4*)(x + base);
            float4 ov;
            ov.x = fmaxf(acc[m][n][0]*scale + shift + res.x, 0.0f);
            ov.y = fmaxf(acc[m][n][1]*scale + shift + res.y, 0.0f);
            ov.z = fmaxf(acc[m][n][2]*scale + shift + res.z, 0.0f);
            ov.w = fmaxf(acc[m][n][3]*scale + shift + res.w, 0.0f);
            *(float4*)(out + base) = ov;
        }
    }
}

// ---------------------------------------------------------------------------
// Fallback (NCHW f32 path) if ws is too small for the transposed copy.
// ---------------------------------------------------------------------------
__global__ __launch_bounds__(256) void deform_conv_kernel(
    const float* __restrict__ x, const float* __restrict__ w_def,
    const float* __restrict__ aff, const float* __restrict__ gamma,
    const float* __restrict__ beta, const float* __restrict__ rmean,
    const float* __restrict__ rvar, float* __restrict__ out)
{
    __shared__ float wl[9*Cg*Cg];
    const int blk  = swizzle_blk(blockIdx.x);
    const int tile = blk % TILES;
    const int g    = (blk / TILES) % G;
    const int b    = blk / (TILES*G);

    for (int l = threadIdx.x; l < 9*Cg*Cg; l += 256) {
        int o = l & 31; int i = (l >> 5) & 31; int k = l >> 10;
        wl[l] = w_def[(size_t)(g*Cg + o)*(Cg*9) + i*9 + k];
    }
    __syncthreads();

    const int p = tile*256 + threadIdx.x;
    const int h = p / W, w = p % W;

    const float* ap = aff + ((size_t)(b*G + g)*6)*HW + p;
    const float a0 = ap[0*(size_t)HW], a1 = ap[1*(size_t)HW], a2 = ap[2*(size_t)HW];
    const float a3 = ap[3*(size_t)HW], a4 = ap[4*(size_t)HW], a5 = ap[5*(size_t)HW];

    float acc[Cg];
    #pragma unroll
    for (int o = 0; o < Cg; ++o) acc[o] = 0.0f;

    const float* xg = x + ((size_t)b*C + g*Cg)*HW;

    #pragma unroll
    for (int k = 0; k < 9; ++k) {
        const float kyf = (float)(k/3 - 1);
        const float kxf = (float)(k%3 - 1);
        const float offy = a0*kyf + a1*kxf + a2;
        const float offx = a3*kyf + a4*kxf + a5;
        const float py = (float)h + kyf + offy;
        const float px = (float)w + kxf + offx;
        const float y0f = floorf(py), x0f = floorf(px);
        const float fy = py - y0f,   fx = px - x0f;
        const int y0 = (int)y0f, x0 = (int)x0f;
        const int y1 = y0 + 1,   x1 = x0 + 1;
        const bool vy0 = (y0 >= 0) && (y0 < H);
        const bool vy1 = (y1 >= 0) && (y1 < H);
        const bool vx0 = (x0 >= 0) && (x0 < W);
        const bool vx1 = (x1 >= 0) && (x1 < W);
        const float w00 = (vy0 && vx0) ? (1.0f - fy)*(1.0f - fx) : 0.0f;
        const float w01 = (vy0 && vx1) ? (1.0f - fy)*fx          : 0.0f;
        const float w10 = (vy1 && vx0) ? fy*(1.0f - fx)          : 0.0f;
        const float w11 = (vy1 && vx1) ? fy*fx                   : 0.0f;
        const int y0c = min(max(y0, 0), H-1), y1c = min(max(y1, 0), H-1);
        const int x0c = min(max(x0, 0), W-1), x1c = min(max(x1, 0), W-1);
        const int p00 = y0c*W + x0c, p01 = y0c*W + x1c;
        const int p10 = y1c*W + x0c, p11 = y1c*W + x1c;

        const float* wk = &wl[k*Cg*Cg];
        for (int i = 0; i < Cg; ++i) {
            const float* xc = xg + (size_t)i*HW;
            const float v = w00*xc[p00] + w01*xc[p01] + w10*xc[p10] + w11*xc[p11];
            #pragma unroll
            for (int o = 0; o < Cg; ++o)
                acc[o] = fmaf(v, wk[i*Cg + o], acc[o]);
        }
    }

    float* op = out + ((size_t)b*C + g*Cg)*HW + p;
    #pragma unroll
    for (int o = 0; o < Cg; ++o) {
        const int c = g*Cg + o;
        const float inv = rsqrtf(rvar[c] + BN_EPS);
        float val = (acc[o] - rmean[c]) * (inv * gamma[c]) + beta[c];
        val += xg[(size_t)o*HW + p];
        op[(size_t)o*HW] = fmaxf(val, 0.0f);
    }
}

// ---------------------------------------------------------------------------
extern "C" void kernel_launch(void* const* d_in, const int* in_sizes, int n_in,
                              void* d_out, int out_size, void* d_ws, size_t ws_size,
                              hipStream_t stream) {
    const float* x     = (const float*)d_in[0];
    const float* w_off = (const float*)d_in[1];
    const float* b_off = (const float*)d_in[2];
    const float* w_def = (const float*)d_in[3];
    const float* gamma = (const float*)d_in[4];
    const float* beta  = (const float*)d_in[5];
    const float* rmean = (const float*)d_in[6];
    const float* rvar  = (const float*)d_in[7];
    float* out = (float*)d_out;

    const size_t AFF_BYTES = (size_t)B*G*6*HW*sizeof(float);   // ~15.0 MB
    const size_t XT_BYTES  = (size_t)B*G*HW*Cg*sizeof(float);  // ~80.2 MB
    float* aff = (float*)d_ws;

    offset_conv_kernel<<<NBLK, 256, 0, stream>>>(x, w_off, b_off, aff);

    if (ws_size >= AFF_BYTES + XT_BYTES) {
        float* xT = (float*)((char*)d_ws + AFF_BYTES);
        transpose_kernel<<<NBLK, 256, 0, stream>>>(x, xT);
        deform_mfma_kernel<<<NBLK, 256, 0, stream>>>(x, xT, w_def, aff, gamma,
                                                     beta, rmean, rvar, out);
    } else {
        deform_conv_kernel<<<NBLK, 256, 0, stream>>>(x, w_def, aff, gamma, beta,
                                                     rmean, rvar, out);
    }
}